// Round 3
// baseline (1463.792 us; speedup 1.0000x reference)
//
#include <hip/hip_runtime.h>

#define N_NODES 20000
#define N_EDGES 640000

// ---------------- k0: zero accumulators (incl. dtype flags) ----------------
__global__ void k0_zero(float4* __restrict__ p, int n4){
    int i = blockIdx.x*blockDim.x + threadIdx.x;
    int stride = gridDim.x*blockDim.x;
    float4 z; z.x=0.f; z.y=0.f; z.z=0.f; z.w=0.f;
    for (; i<n4; i+=stride) p[i] = z;
}

// ---------------- kD: detect int32 vs int64 index buffers ----------------
// int64 values here are small non-negative -> every odd 32-bit word of the
// guaranteed prefix is 0. flags[0]!=0 => eidx is int32; flags[1]!=0 => etype is int32.
__global__ void kD_detect(const int* __restrict__ eidx_w, const int* __restrict__ ety_w,
                          int* __restrict__ flags){
    int i = blockIdx.x*blockDim.x + threadIdx.x;
    int stride = gridDim.x*blockDim.x;
    int a0 = 0, a1 = 0;
    // guaranteed sizes (int32 interpretation): eidx >= 2E words, etype >= E words
    for (int w = 2*i+1; w < 2*N_EDGES; w += 2*stride) a0 |= eidx_w[w];
    for (int w = 2*i+1; w < N_EDGES;   w += 2*stride) a1 |= ety_w[w];
    if (a0) atomicOr(&flags[0], 1);
    if (a1) atomicOr(&flags[1], 1);
}

// ---------------- kN: normalize indices to int32 src/dst/ty ----------------
__global__ void kN_norm(const int* __restrict__ eidx_w, const int* __restrict__ ety_w,
                        const int* __restrict__ flags,
                        int* __restrict__ src, int* __restrict__ dst, int* __restrict__ ty){
    int i = blockIdx.x*blockDim.x + threadIdx.x;
    int stride = gridDim.x*blockDim.x;
    const bool e32 = (flags[0] != 0);
    const bool t32 = (flags[1] != 0);
    for (int e = i; e < N_EDGES; e += stride){
        int s, d, t;
        if (e32){ s = eidx_w[e];   d = eidx_w[N_EDGES + e]; }
        else    { s = eidx_w[2*e]; d = eidx_w[2*N_EDGES + 2*e]; }
        t = t32 ? ety_w[e] : ety_w[2*e];
        // defensive clamp: never fault even if interpretation is off
        s = min(max(s, 0), N_NODES-1);
        d = min(max(d, 0), N_NODES-1);
        t = min(max(t, 0), 15);
        src[e] = s; dst[e] = d; ty[e] = t;
    }
}

// ---------------- k1: per-node transform h = x@gat_W, a_s, a_d ----------------
__global__ __launch_bounds__(128) void k1_node_prep(
    const float* __restrict__ x, const float* __restrict__ gat_W,
    const float* __restrict__ a_src, const float* __restrict__ a_dst,
    float* __restrict__ h_out, float* __restrict__ as_out, float* __restrict__ ad_out)
{
    __shared__ float sX[128];
    const int n = blockIdx.x;
    const int t = threadIdx.x;
    sX[t] = x[n*128 + t];
    __syncthreads();
    float acc = 0.f;
    #pragma unroll 8
    for (int k=0;k<128;k++) acc += sX[k]*gat_W[k*128 + t];
    h_out[n*128 + t] = acc;
    float vs = acc*a_src[t];   // a_src[hh][c], flat index == t
    float vd = acc*a_dst[t];
    #pragma unroll
    for (int off=8; off>=1; off>>=1){ vs += __shfl_xor(vs,off,16); vd += __shfl_xor(vd,off,16); }
    if ((t&15)==0){ as_out[n*8 + (t>>4)] = vs; ad_out[n*8 + (t>>4)] = vd; }
}

// ---------------- k2: per-edge pass A (GAT logits/p + GINE scatter) ----------------
__global__ __launch_bounds__(256) void k2_edge_a(
    const float* __restrict__ x,
    const int* __restrict__ src_a, const int* __restrict__ dst_a, const int* __restrict__ ty_a,
    const float* __restrict__ eattr,
    const float* __restrict__ gat_edge_W, const float* __restrict__ a_edge,
    const float* __restrict__ gat_emb, const float* __restrict__ gine_emb,
    const float* __restrict__ gine_edge_W, const float* __restrict__ gine_edge_b,
    const float* __restrict__ a_s, const float* __restrict__ a_d,
    float* __restrict__ p_ws, float* __restrict__ denom, float* __restrict__ agg)
{
    __shared__ float sGatW[32*128];
    __shared__ float sGineW[32*128];
    __shared__ float sAe[128];
    __shared__ float sGatEmb[16*32];
    __shared__ float sGineEmb[16*32];
    __shared__ float sGineB[128];
    __shared__ float sEvG[2][32];
    __shared__ float sEvE[2][32];
    const int t = threadIdx.x;
    for (int i=t;i<4096;i+=256){ sGatW[i]=gat_edge_W[i]; sGineW[i]=gine_edge_W[i]; }
    for (int i=t;i<512;i+=256){ sGatEmb[i]=gat_emb[i]; sGineEmb[i]=gine_emb[i]; }
    if (t<128){ sAe[t]=a_edge[t]; sGineB[t]=gine_edge_b[t]; }
    const int slot = t>>7;
    const int j = t&127;
    const int hh = j>>4;
    for (int e0 = blockIdx.x*2; e0 < N_EDGES; e0 += gridDim.x*2) {
        const int e = e0 + slot;
        __syncthreads();   // covers preload on first iter, prev-iter readers after
        if (j < 32){
            int tyv = ty_a[e];
            float ea = eattr[e*32 + j];
            sEvG[slot][j] = ea + sGatEmb[tyv*32 + j];
            sEvE[slot][j] = ea + sGineEmb[tyv*32 + j];
        }
        __syncthreads();
        const int src = src_a[e];
        const int dst = dst_a[e];
        float aG = 0.f, aE = 0.f;
        #pragma unroll 8
        for (int k=0;k<32;k++){
            aG += sEvG[slot][k]*sGatW[k*128 + j];
            aE += sEvE[slot][k]*sGineW[k*128 + j];
        }
        // GINE: relu(x[src] + ep) scatter-add
        float msg = x[src*128 + j] + aE + sGineB[j];
        msg = fmaxf(msg, 0.f);
        atomicAdd(&agg[dst*128 + j], msg);
        // GAT: a_e per-head reduction, logit, p
        float v = aG*sAe[j];
        #pragma unroll
        for (int off=8; off>=1; off>>=1) v += __shfl_xor(v,off,16);
        float lg = a_s[src*8 + hh] + a_d[dst*8 + hh] + v;
        lg = (lg > 0.f) ? lg : 0.2f*lg;
        float pv = __expf(lg);   // logits are O(0.1): max-shift unnecessary
        if ((j&15)==0){
            p_ws[e*8 + hh] = pv;
            atomicAdd(&denom[dst*8 + hh], pv);
        }
    }
}

// ---------------- k3: per-edge pass B (alpha * h[src] scatter) ----------------
__global__ __launch_bounds__(256) void k3_edge_b(
    const int* __restrict__ src_a, const int* __restrict__ dst_a,
    const float* __restrict__ hws,
    const float* __restrict__ p_ws, const float* __restrict__ denom,
    float* __restrict__ gat_acc)
{
    const int t = threadIdx.x;
    const int e = blockIdx.x*2 + (t>>7);
    const int j = t&127;
    const int hh = j>>4;
    const int src = src_a[e];
    const int dst = dst_a[e];
    float alpha = p_ws[e*8 + hh] / (denom[dst*8 + hh] + 1e-16f);
    float v = alpha * hws[src*128 + j];
    atomicAdd(&gat_acc[dst*128 + j], v);
}

// ---------------- k4: final node kernel (GINE MLP + comb + LN + ReLU) ----------------
#define NPB 4
__global__ __launch_bounds__(256) void k4_final(
    const float* __restrict__ x, const float* __restrict__ agg, const float* __restrict__ gat_acc,
    const float* __restrict__ gat_b, const float* __restrict__ eps_p,
    const float* __restrict__ W1, const float* __restrict__ b1,
    const float* __restrict__ W2, const float* __restrict__ gb2,
    const float* __restrict__ comb_W, const float* __restrict__ comb_b,
    const float* __restrict__ ln_g, const float* __restrict__ ln_b,
    float* __restrict__ out)
{
    __shared__ float sZin[NPB][256];
    __shared__ float sH2[128];
    __shared__ float sT1[128];
    __shared__ float sP1[4], sP2[4];
    __shared__ float sMu, sRs;
    const int t = threadIdx.x;
    const float epsv = 1.f + eps_p[0];

    for (int nn=0; nn<NPB; nn++){
        const int n = blockIdx.x*NPB + nn;
        if (t < 128){
            sH2[t] = epsv*x[n*128 + t] + agg[n*128 + t];
        } else {
            int jj = t - 128;
            sZin[nn][jj] = gat_acc[n*128 + jj] + gat_b[jj];
        }
        __syncthreads();
        if (t < 128){
            float acc = b1[t];
            #pragma unroll 8
            for (int k=0;k<128;k++) acc += sH2[k]*W1[k*128 + t];
            sT1[t] = fmaxf(acc, 0.f);
        }
        __syncthreads();
        if (t < 128){
            float acc = gb2[t];
            #pragma unroll 8
            for (int k=0;k<128;k++) acc += sT1[k]*W2[k*128 + t];
            sZin[nn][128 + t] = acc;
        }
        __syncthreads();
    }

    // comb: z[nn][t] = comb_b[t] + sum_k zin[nn][k] * comb_W[k][t]
    float z[NPB];
    const float cb = comb_b[t];
    #pragma unroll
    for (int nn=0;nn<NPB;nn++) z[nn] = cb;
    for (int k=0;k<256;k++){
        float w = comb_W[k*256 + t];
        #pragma unroll
        for (int nn=0;nn<NPB;nn++) z[nn] += sZin[nn][k]*w;
    }

    const float g  = ln_g[t];
    const float bb = ln_b[t];
    for (int nn=0;nn<NPB;nn++){
        const int n = blockIdx.x*NPB + nn;
        float zv = z[nn];
        float s1 = zv, s2 = zv*zv;
        #pragma unroll
        for (int off=32; off>=1; off>>=1){ s1 += __shfl_xor(s1,off,64); s2 += __shfl_xor(s2,off,64); }
        if ((t&63)==0){ sP1[t>>6]=s1; sP2[t>>6]=s2; }
        __syncthreads();
        if (t==0){
            float a1 = sP1[0]+sP1[1]+sP1[2]+sP1[3];
            float a2 = sP2[0]+sP2[1]+sP2[2]+sP2[3];
            float mu = a1*(1.f/256.f);
            float var = a2*(1.f/256.f) - mu*mu;
            sMu = mu; sRs = rsqrtf(var + 1e-5f);
        }
        __syncthreads();
        float r = (zv - sMu)*sRs*g + bb;
        out[n*256 + t] = fmaxf(r, 0.f);
        __syncthreads();
    }
}

extern "C" void kernel_launch(void* const* d_in, const int* in_sizes, int n_in,
                              void* d_out, int out_size, void* d_ws, size_t ws_size,
                              hipStream_t stream)
{
    (void)in_sizes; (void)n_in; (void)out_size; (void)ws_size;
    const float* x           = (const float*)d_in[0];
    const int*   eidx_w      = (const int*)  d_in[1];   // int32 or int64 words — sniffed
    const float* eattr       = (const float*)d_in[2];
    const int*   ety_w       = (const int*)  d_in[3];   // int32 or int64 words — sniffed
    const float* gat_W       = (const float*)d_in[4];
    const float* gat_b       = (const float*)d_in[5];
    const float* gat_edge_W  = (const float*)d_in[6];
    const float* a_src       = (const float*)d_in[7];
    const float* a_dst       = (const float*)d_in[8];
    const float* a_edge      = (const float*)d_in[9];
    const float* gat_emb     = (const float*)d_in[10];
    const float* gine_emb    = (const float*)d_in[11];
    const float* gine_edge_W = (const float*)d_in[12];
    const float* gine_edge_b = (const float*)d_in[13];
    const float* gine_eps    = (const float*)d_in[14];
    const float* W1          = (const float*)d_in[15];
    const float* b1          = (const float*)d_in[16];
    const float* W2          = (const float*)d_in[17];
    const float* gb2         = (const float*)d_in[18];
    const float* comb_W      = (const float*)d_in[19];
    const float* comb_b      = (const float*)d_in[20];
    const float* ln_g        = (const float*)d_in[21];
    const float* ln_b        = (const float*)d_in[22];
    float* out = (float*)d_out;

    char* ws = (char*)d_ws;
    size_t off = 0;
    auto alloc = [&](size_t bytes)->void*{ void* p = ws + off; off += (bytes + 255)/256*256; return p; };
    int*   srcA  = (int*)  alloc((size_t)N_EDGES*4);
    int*   dstA  = (int*)  alloc((size_t)N_EDGES*4);
    int*   tyA   = (int*)  alloc((size_t)N_EDGES*4);
    float* hws   = (float*)alloc((size_t)N_NODES*128*4);
    float* a_s   = (float*)alloc((size_t)N_NODES*8*4);
    float* a_d   = (float*)alloc((size_t)N_NODES*8*4);
    float* p_ws  = (float*)alloc((size_t)N_EDGES*8*4);
    // flags + the three accumulators are contiguous: one zero-kernel covers them
    size_t zero_start = off;
    int*   flags = (int*)  alloc(256);
    float* denom = (float*)alloc((size_t)N_NODES*8*4);
    float* agg   = (float*)alloc((size_t)N_NODES*128*4);
    float* gacc  = (float*)alloc((size_t)N_NODES*128*4);
    size_t zero_bytes = off - zero_start;   // 256-aligned, divisible by 16

    int n4 = (int)(zero_bytes/16);
    k0_zero<<<2048, 256, 0, stream>>>((float4*)(ws + zero_start), n4);
    kD_detect<<<512, 256, 0, stream>>>(eidx_w, ety_w, flags);
    kN_norm<<<1024, 256, 0, stream>>>(eidx_w, ety_w, flags, srcA, dstA, tyA);

    k1_node_prep<<<N_NODES, 128, 0, stream>>>(x, gat_W, a_src, a_dst, hws, a_s, a_d);
    k2_edge_a<<<2560, 256, 0, stream>>>(x, srcA, dstA, tyA, eattr, gat_edge_W, a_edge,
                                        gat_emb, gine_emb, gine_edge_W, gine_edge_b,
                                        a_s, a_d, p_ws, denom, agg);
    k3_edge_b<<<N_EDGES/2, 256, 0, stream>>>(srcA, dstA, hws, p_ws, denom, gacc);
    k4_final<<<N_NODES/NPB, 256, 0, stream>>>(x, agg, gacc, gat_b, gine_eps,
                                              W1, b1, W2, gb2, comb_W, comb_b,
                                              ln_g, ln_b, out);
}

// Round 4
// 1062.084 us; speedup vs baseline: 1.3782x; 1.3782x over previous
//
#include <hip/hip_runtime.h>

#define N_NODES 20000
#define N_EDGES 640000

// ---------------- k0: zero flags + histogram counters ----------------
__global__ void k0_zero(float4* __restrict__ p, int n4){
    int i = blockIdx.x*blockDim.x + threadIdx.x;
    int stride = gridDim.x*blockDim.x;
    float4 z; z.x=0.f; z.y=0.f; z.z=0.f; z.w=0.f;
    for (; i<n4; i+=stride) p[i] = z;
}

// ---------------- kD: detect int32 vs int64 index buffers ----------------
__global__ void kD_detect(const int* __restrict__ eidx_w, const int* __restrict__ ety_w,
                          int* __restrict__ flags){
    int i = blockIdx.x*blockDim.x + threadIdx.x;
    int stride = gridDim.x*blockDim.x;
    int a0 = 0, a1 = 0;
    for (int w = 2*i+1; w < 2*N_EDGES; w += 2*stride) a0 |= eidx_w[w];
    for (int w = 2*i+1; w < N_EDGES;   w += 2*stride) a1 |= ety_w[w];
    if (a0) atomicOr(&flags[0], 1);
    if (a1) atomicOr(&flags[1], 1);
}

// ---------------- kN: normalize indices to int32 src/dst/ty ----------------
__global__ void kN_norm(const int* __restrict__ eidx_w, const int* __restrict__ ety_w,
                        const int* __restrict__ flags,
                        int* __restrict__ src, int* __restrict__ dst, int* __restrict__ ty){
    int i = blockIdx.x*blockDim.x + threadIdx.x;
    int stride = gridDim.x*blockDim.x;
    const bool e32 = (flags[0] != 0);
    const bool t32 = (flags[1] != 0);
    for (int e = i; e < N_EDGES; e += stride){
        int s, d, t;
        if (e32){ s = eidx_w[e];   d = eidx_w[N_EDGES + e]; }
        else    { s = eidx_w[2*e]; d = eidx_w[2*N_EDGES + 2*e]; }
        t = t32 ? ety_w[e] : ety_w[2*e];
        s = min(max(s, 0), N_NODES-1);
        d = min(max(d, 0), N_NODES-1);
        t = min(max(t, 0), 15);
        src[e] = s; dst[e] = d; ty[e] = t;
    }
}

// ---------------- kH: histogram of dst ----------------
__global__ void kH_hist(const int* __restrict__ dst, int* __restrict__ cnt){
    int i = blockIdx.x*blockDim.x + threadIdx.x;
    int stride = gridDim.x*blockDim.x;
    for (int e = i; e < N_EDGES; e += stride) atomicAdd(&cnt[dst[e]], 1);
}

// ---------------- kS: exclusive scan -> row_ptr, cursor (single block) ----------------
__global__ __launch_bounds__(1024) void kS_scan(const int* __restrict__ cnt,
                                                int* __restrict__ row_ptr,
                                                int* __restrict__ cursor){
    __shared__ int s[1024];
    __shared__ int sbase;
    const int t = threadIdx.x;
    if (t==0) sbase = 0;
    __syncthreads();
    for (int base=0; base<N_NODES; base+=1024){
        int idx = base + t;
        int v = (idx<N_NODES) ? cnt[idx] : 0;
        s[t] = v;
        __syncthreads();
        for (int off=1; off<1024; off<<=1){
            int add = (t>=off) ? s[t-off] : 0;
            __syncthreads();
            s[t] += add;
            __syncthreads();
        }
        int excl = sbase + s[t] - v;
        if (idx < N_NODES){ row_ptr[idx] = excl; cursor[idx] = excl; }
        __syncthreads();
        if (t==0) sbase = sbase + s[1023];
        __syncthreads();
    }
    if (t==0) row_ptr[N_NODES] = sbase;
}

// ---------------- kC: scatter edges into CSR order ----------------
__global__ void kC_scatter(const int* __restrict__ src, const int* __restrict__ dst,
                           const int* __restrict__ ty, int* __restrict__ cursor,
                           int* __restrict__ eid_s, int* __restrict__ srcty_s){
    int i = blockIdx.x*blockDim.x + threadIdx.x;
    int stride = gridDim.x*blockDim.x;
    for (int e = i; e < N_EDGES; e += stride){
        int pos = atomicAdd(&cursor[dst[e]], 1);
        eid_s[pos] = e;
        srcty_s[pos] = src[e] | (ty[e] << 20);
    }
}

// ---------------- kM: M[d][h] = sum_c gatW[d,h*16+c]*a_edge[h,c]; AT[ty][h] ----------------
__global__ __launch_bounds__(256) void kM_pre(const float* __restrict__ gat_edge_W,
                                              const float* __restrict__ a_edge,
                                              const float* __restrict__ gat_emb,
                                              float* __restrict__ Mw, float* __restrict__ ATw){
    __shared__ float sM[32*8];
    const int t = threadIdx.x;
    const int d = t>>3, hh = t&7;
    float acc = 0.f;
    #pragma unroll
    for (int c=0;c<16;c++) acc += gat_edge_W[d*128 + hh*16 + c]*a_edge[hh*16 + c];
    sM[d*8+hh] = acc; Mw[d*8+hh] = acc;
    __syncthreads();
    if (t < 128){
        int tyv = t>>3, h2 = t&7;
        float a = 0.f;
        #pragma unroll
        for (int dd=0;dd<32;dd++) a += gat_emb[tyv*32+dd]*sM[dd*8+h2];
        ATw[tyv*8+h2] = a;
    }
}

// ---------------- kT: T[ty][j] = gine_emb[ty]@gine_edge_W + gine_edge_b ----------------
__global__ __launch_bounds__(128) void kT_pre(const float* __restrict__ gine_emb,
                                              const float* __restrict__ gine_edge_W,
                                              const float* __restrict__ gine_edge_b,
                                              float* __restrict__ Tw){
    const int tyv = blockIdx.x;
    const int j = threadIdx.x;
    float acc = gine_edge_b[j];
    #pragma unroll
    for (int d=0;d<32;d++) acc += gine_emb[tyv*32+d]*gine_edge_W[d*128+j];
    Tw[tyv*128+j] = acc;
}

// ---------------- k1: per-node transform h = x@gat_W, a_s, a_d ----------------
__global__ __launch_bounds__(128) void k1_node_prep(
    const float* __restrict__ x, const float* __restrict__ gat_W,
    const float* __restrict__ a_src, const float* __restrict__ a_dst,
    float* __restrict__ h_out, float* __restrict__ as_out, float* __restrict__ ad_out)
{
    __shared__ float sX[128];
    const int n = blockIdx.x;
    const int t = threadIdx.x;
    sX[t] = x[n*128 + t];
    __syncthreads();
    float acc = 0.f;
    #pragma unroll 8
    for (int k=0;k<128;k++) acc += sX[k]*gat_W[k*128 + t];
    h_out[n*128 + t] = acc;
    float vs = acc*a_src[t];
    float vd = acc*a_dst[t];
    #pragma unroll
    for (int off=8; off>=1; off>>=1){ vs += __shfl_xor(vs,off,16); vd += __shfl_xor(vd,off,16); }
    if ((t&15)==0){ as_out[n*8 + (t>>4)] = vs; ad_out[n*8 + (t>>4)] = vd; }
}

// ---------------- k3: per-node CSR aggregation (GAT + GINE, no atomics) ----------------
__global__ __launch_bounds__(128) void k3_csr(
    const float* __restrict__ x, const float* __restrict__ h, const float* __restrict__ eattr,
    const float* __restrict__ a_s, const float* __restrict__ a_d,
    const int* __restrict__ row_ptr, const int* __restrict__ eid_s, const int* __restrict__ srcty_s,
    const float* __restrict__ Mw, const float* __restrict__ ATw, const float* __restrict__ Tw,
    const float* __restrict__ gine_W,
    float* __restrict__ agg, float* __restrict__ gacc)
{
    __shared__ float sT[16*128];
    __shared__ float sAT[16*8];
    const int t = threadIdx.x;      // 0..127, one node per block
    const int d = blockIdx.x;
    const int j = t;
    const int hh = j>>4;
    for (int i=t;i<2048;i+=128) sT[i]=Tw[i];
    if (t<128) sAT[t]=ATw[t];
    // per-thread weight columns in registers (no LDS in hot loop)
    float wcol[32], mcol[32];
    #pragma unroll
    for (int k=0;k<32;k++){ wcol[k]=gine_W[k*128 + j]; mcol[k]=Mw[k*8 + hh]; }
    const float adv = a_d[d*8 + hh];
    __syncthreads();
    const int row = row_ptr[d], end = row_ptr[d+1];
    float accA = 0.f, accG = 0.f, ps = 0.f;
    int i = row;
    for (; i+1 < end; i += 2){
        int e0 = eid_s[i],   e1 = eid_s[i+1];
        int st0 = srcty_s[i], st1 = srcty_s[i+1];
        int s0 = st0 & 0xFFFFF, ty0 = ((unsigned)st0)>>20;
        int s1 = st1 & 0xFFFFF, ty1 = ((unsigned)st1)>>20;
        float ev0 = eattr[e0*32 + (t&31)];
        float ev1 = eattr[e1*32 + (t&31)];
        float xv0 = x[s0*128 + j], hv0 = h[s0*128 + j];
        float xv1 = x[s1*128 + j], hv1 = h[s1*128 + j];
        float as0 = a_s[s0*8 + hh], as1 = a_s[s1*8 + hh];
        float aE0=0.f, ae0=0.f, aE1=0.f, ae1=0.f;
        #pragma unroll
        for (int k=0;k<32;k++){
            float v0 = __shfl(ev0, k, 64);
            float v1 = __shfl(ev1, k, 64);
            aE0 += v0*wcol[k]; ae0 += v0*mcol[k];
            aE1 += v1*wcol[k]; ae1 += v1*mcol[k];
        }
        float ep0 = aE0 + sT[ty0*128 + j];
        float ep1 = aE1 + sT[ty1*128 + j];
        float lg0 = as0 + adv + ae0 + sAT[ty0*8 + hh];
        float lg1 = as1 + adv + ae1 + sAT[ty1*8 + hh];
        lg0 = (lg0 > 0.f) ? lg0 : 0.2f*lg0;
        lg1 = (lg1 > 0.f) ? lg1 : 0.2f*lg1;
        float p0 = __expf(lg0), p1 = __expf(lg1);
        accA += fmaxf(xv0 + ep0, 0.f) + fmaxf(xv1 + ep1, 0.f);
        accG += p0*hv0 + p1*hv1;
        ps   += p0 + p1;
    }
    if (i < end){
        int e0 = eid_s[i];
        int st0 = srcty_s[i];
        int s0 = st0 & 0xFFFFF, ty0 = ((unsigned)st0)>>20;
        float ev0 = eattr[e0*32 + (t&31)];
        float xv0 = x[s0*128 + j], hv0 = h[s0*128 + j];
        float as0 = a_s[s0*8 + hh];
        float aE0=0.f, ae0=0.f;
        #pragma unroll
        for (int k=0;k<32;k++){
            float v0 = __shfl(ev0, k, 64);
            aE0 += v0*wcol[k]; ae0 += v0*mcol[k];
        }
        float ep0 = aE0 + sT[ty0*128 + j];
        float lg0 = as0 + adv + ae0 + sAT[ty0*8 + hh];
        lg0 = (lg0 > 0.f) ? lg0 : 0.2f*lg0;
        float p0 = __expf(lg0);
        accA += fmaxf(xv0 + ep0, 0.f);
        accG += p0*hv0;
        ps   += p0;
    }
    agg[d*128 + j]  = accA;
    gacc[d*128 + j] = accG / (ps + 1e-16f);   // == sum(alpha*h), alpha = p/(sum p + 1e-16)
}

// ---------------- k4: final node kernel (GINE MLP + comb + LN + ReLU) ----------------
#define NPB 4
__global__ __launch_bounds__(256) void k4_final(
    const float* __restrict__ x, const float* __restrict__ agg, const float* __restrict__ gat_acc,
    const float* __restrict__ gat_b, const float* __restrict__ eps_p,
    const float* __restrict__ W1, const float* __restrict__ b1,
    const float* __restrict__ W2, const float* __restrict__ gb2,
    const float* __restrict__ comb_W, const float* __restrict__ comb_b,
    const float* __restrict__ ln_g, const float* __restrict__ ln_b,
    float* __restrict__ out)
{
    __shared__ float sZin[NPB][256];
    __shared__ float sH2[128];
    __shared__ float sT1[128];
    __shared__ float sP1[4], sP2[4];
    __shared__ float sMu, sRs;
    const int t = threadIdx.x;
    const float epsv = 1.f + eps_p[0];

    for (int nn=0; nn<NPB; nn++){
        const int n = blockIdx.x*NPB + nn;
        if (t < 128){
            sH2[t] = epsv*x[n*128 + t] + agg[n*128 + t];
        } else {
            int jj = t - 128;
            sZin[nn][jj] = gat_acc[n*128 + jj] + gat_b[jj];
        }
        __syncthreads();
        if (t < 128){
            float acc = b1[t];
            #pragma unroll 8
            for (int k=0;k<128;k++) acc += sH2[k]*W1[k*128 + t];
            sT1[t] = fmaxf(acc, 0.f);
        }
        __syncthreads();
        if (t < 128){
            float acc = gb2[t];
            #pragma unroll 8
            for (int k=0;k<128;k++) acc += sT1[k]*W2[k*128 + t];
            sZin[nn][128 + t] = acc;
        }
        __syncthreads();
    }

    float z[NPB];
    const float cb = comb_b[t];
    #pragma unroll
    for (int nn=0;nn<NPB;nn++) z[nn] = cb;
    for (int k=0;k<256;k++){
        float w = comb_W[k*256 + t];
        #pragma unroll
        for (int nn=0;nn<NPB;nn++) z[nn] += sZin[nn][k]*w;
    }

    const float g  = ln_g[t];
    const float bb = ln_b[t];
    for (int nn=0;nn<NPB;nn++){
        const int n = blockIdx.x*NPB + nn;
        float zv = z[nn];
        float s1 = zv, s2 = zv*zv;
        #pragma unroll
        for (int off=32; off>=1; off>>=1){ s1 += __shfl_xor(s1,off,64); s2 += __shfl_xor(s2,off,64); }
        if ((t&63)==0){ sP1[t>>6]=s1; sP2[t>>6]=s2; }
        __syncthreads();
        if (t==0){
            float a1 = sP1[0]+sP1[1]+sP1[2]+sP1[3];
            float a2 = sP2[0]+sP2[1]+sP2[2]+sP2[3];
            float mu = a1*(1.f/256.f);
            float var = a2*(1.f/256.f) - mu*mu;
            sMu = mu; sRs = rsqrtf(var + 1e-5f);
        }
        __syncthreads();
        float r = (zv - sMu)*sRs*g + bb;
        out[n*256 + t] = fmaxf(r, 0.f);
        __syncthreads();
    }
}

extern "C" void kernel_launch(void* const* d_in, const int* in_sizes, int n_in,
                              void* d_out, int out_size, void* d_ws, size_t ws_size,
                              hipStream_t stream)
{
    (void)in_sizes; (void)n_in; (void)out_size; (void)ws_size;
    const float* x           = (const float*)d_in[0];
    const int*   eidx_w      = (const int*)  d_in[1];
    const float* eattr       = (const float*)d_in[2];
    const int*   ety_w       = (const int*)  d_in[3];
    const float* gat_W       = (const float*)d_in[4];
    const float* gat_b       = (const float*)d_in[5];
    const float* gat_edge_W  = (const float*)d_in[6];
    const float* a_src       = (const float*)d_in[7];
    const float* a_dst       = (const float*)d_in[8];
    const float* a_edge      = (const float*)d_in[9];
    const float* gat_emb     = (const float*)d_in[10];
    const float* gine_emb    = (const float*)d_in[11];
    const float* gine_edge_W = (const float*)d_in[12];
    const float* gine_edge_b = (const float*)d_in[13];
    const float* gine_eps    = (const float*)d_in[14];
    const float* W1          = (const float*)d_in[15];
    const float* b1          = (const float*)d_in[16];
    const float* W2          = (const float*)d_in[17];
    const float* gb2         = (const float*)d_in[18];
    const float* comb_W      = (const float*)d_in[19];
    const float* comb_b      = (const float*)d_in[20];
    const float* ln_g        = (const float*)d_in[21];
    const float* ln_b        = (const float*)d_in[22];
    float* out = (float*)d_out;

    char* ws = (char*)d_ws;
    size_t off = 0;
    auto alloc = [&](size_t bytes)->void*{ void* p = ws + off; off += (bytes + 255)/256*256; return p; };
    // zeroed region first: flags + cnt
    size_t zero_start = off;
    int*   flags  = (int*)  alloc(256);
    int*   cnt    = (int*)  alloc((size_t)N_NODES*4);
    size_t zero_bytes = off - zero_start;
    int*   srcA   = (int*)  alloc((size_t)N_EDGES*4);
    int*   dstA   = (int*)  alloc((size_t)N_EDGES*4);
    int*   tyA    = (int*)  alloc((size_t)N_EDGES*4);
    int*   rowp   = (int*)  alloc((size_t)(N_NODES+1)*4);
    int*   cursor = (int*)  alloc((size_t)N_NODES*4);
    int*   eid_s  = (int*)  alloc((size_t)N_EDGES*4);
    int*   srcty  = (int*)  alloc((size_t)N_EDGES*4);
    float* hws    = (float*)alloc((size_t)N_NODES*128*4);
    float* a_s    = (float*)alloc((size_t)N_NODES*8*4);
    float* a_d    = (float*)alloc((size_t)N_NODES*8*4);
    float* Mw     = (float*)alloc(32*8*4);
    float* ATw    = (float*)alloc(16*8*4);
    float* Tw     = (float*)alloc(16*128*4);
    float* agg    = (float*)alloc((size_t)N_NODES*128*4);
    float* gacc   = (float*)alloc((size_t)N_NODES*128*4);

    int n4 = (int)(zero_bytes/16);
    k0_zero<<<(n4+255)/256, 256, 0, stream>>>((float4*)(ws + zero_start), n4);
    kD_detect<<<512, 256, 0, stream>>>(eidx_w, ety_w, flags);
    kN_norm<<<1024, 256, 0, stream>>>(eidx_w, ety_w, flags, srcA, dstA, tyA);

    kH_hist<<<1024, 256, 0, stream>>>(dstA, cnt);
    kS_scan<<<1, 1024, 0, stream>>>(cnt, rowp, cursor);
    kC_scatter<<<1024, 256, 0, stream>>>(srcA, dstA, tyA, cursor, eid_s, srcty);

    kM_pre<<<1, 256, 0, stream>>>(gat_edge_W, a_edge, gat_emb, Mw, ATw);
    kT_pre<<<16, 128, 0, stream>>>(gine_emb, gine_edge_W, gine_edge_b, Tw);
    k1_node_prep<<<N_NODES, 128, 0, stream>>>(x, gat_W, a_src, a_dst, hws, a_s, a_d);

    k3_csr<<<N_NODES, 128, 0, stream>>>(x, hws, eattr, a_s, a_d, rowp, eid_s, srcty,
                                        Mw, ATw, Tw, gine_edge_W, agg, gacc);

    k4_final<<<N_NODES/NPB, 256, 0, stream>>>(x, agg, gacc, gat_b, gine_eps,
                                              W1, b1, W2, gb2, comb_W, comb_b,
                                              ln_g, ln_b, out);
}